// Round 10
// baseline (559.078 us; speedup 1.0000x reference)
//
#include <hip/hip_runtime.h>

#define BN 16384
#define DD 16
#define KNN 25
#define QB 8
#define MSUB 2048
#define CAP 384

typedef unsigned long long u64;

__device__ __forceinline__ u64 wave_min_u64(u64 v) {
#pragma unroll
    for (int off = 32; off >= 1; off >>= 1) {
        unsigned lo = (unsigned)v, hi = (unsigned)(v >> 32);
        unsigned olo = __shfl_xor(lo, off, 64);
        unsigned ohi = __shfl_xor(hi, off, 64);
        u64 o = (((u64)ohi) << 32) | olo;
        if (o < v) v = o;
    }
    return v;
}

// scalar 16-term fma dot; identical chain for qn => exact self-zero
__device__ __forceinline__ float dot16v(float4 qa, float4 qb, float4 qc, float4 qd,
                                        float4 pa, float4 pb, float4 pc, float4 pd) {
    float s = qa.x * pa.x;
    s = fmaf(qa.y, pa.y, s); s = fmaf(qa.z, pa.z, s); s = fmaf(qa.w, pa.w, s);
    s = fmaf(qb.x, pb.x, s); s = fmaf(qb.y, pb.y, s); s = fmaf(qb.z, pb.z, s);
    s = fmaf(qb.w, pb.w, s); s = fmaf(qc.x, pc.x, s); s = fmaf(qc.y, pc.y, s);
    s = fmaf(qc.z, pc.z, s); s = fmaf(qc.w, pc.w, s); s = fmaf(qd.x, pd.x, s);
    s = fmaf(qd.y, pd.y, s); s = fmaf(qd.z, pd.z, s); s = fmaf(qd.w, pd.w, s);
    return s;
}

// ---------------- norms ----------------
__global__ void norms_kernel(const float* __restrict__ raw, float* __restrict__ nrm) {
    int j = blockIdx.x * 256 + threadIdx.x;
    if (j < BN) {
        const float4* rv = (const float4*)raw + j * 4;
        float4 a = rv[0], b = rv[1], c = rv[2], d = rv[3];
        nrm[j] = dot16v(a, b, c, d, a, b, c, d);
    }
}

// ---------------- recon partials ----------------
__global__ void recon_kernel(const float* __restrict__ o, const float* __restrict__ t,
                             float* __restrict__ part) {
    __shared__ float red[256];
    int tid = threadIdx.x;
    int idx = blockIdx.x * 256 + tid;
    float s = 0.f;
    for (int i = idx; i < BN * DD; i += 256 * 256) {
        float d = o[i] - t[i];
        s = fmaf(d, d, s);
    }
    red[tid] = s;
    __syncthreads();
    for (int off = 128; off > 0; off >>= 1) {
        if (tid < off) red[tid] += red[tid + off];
        __syncthreads();
    }
    if (tid == 0) part[blockIdx.x] = red[0];
}

// ---------------- main: 8 rows per block ----------------
__global__ __launch_bounds__(256, 5) void tsa_kernel(const float* __restrict__ latent,
                                                     const float* __restrict__ raw,
                                                     const float* __restrict__ nrm,
                                                     float* __restrict__ tsa) {
    const int tid  = threadIdx.x;
    const int lane = tid & 63;
    const int w    = tid >> 6;
    const int row0 = blockIdx.x * QB;

    // 24.6 KB overlay: phase A = minbuf (8 KB), phase B/select = lists (24.6 KB),
    // eigen = per-wave scratch (4 x 5 KB)
    __shared__ __align__(16) char smem[QB * CAP * 8];
    float (*listV)[CAP] = (float (*)[CAP])smem;
    int   (*listI)[CAP] = (int (*)[CAP])(smem + QB * CAP * 4);
    float (*minbuf)[256] = (float (*)[256])smem;

    __shared__ int   lcnt[QB];
    __shared__ float Bv[QB];
    __shared__ int   nbr[QB][KNN];

    if (tid < QB) lcnt[tid] = 0;
    __syncthreads();

    const float4* rv4 = (const float4*)raw;

    // ---- queries -> named vars (block-uniform; compiler scalarizes) ----
#define LQ(qi) \
    float4 q##qi##a = rv4[(row0 + qi) * 4 + 0]; \
    float4 q##qi##b = rv4[(row0 + qi) * 4 + 1]; \
    float4 q##qi##c = rv4[(row0 + qi) * 4 + 2]; \
    float4 q##qi##d = rv4[(row0 + qi) * 4 + 3]; \
    float qn##qi = dot16v(q##qi##a, q##qi##b, q##qi##c, q##qi##d, \
                          q##qi##a, q##qi##b, q##qi##c, q##qi##d);
    LQ(0) LQ(1) LQ(2) LQ(3) LQ(4) LQ(5) LQ(6) LQ(7)

    // ---- phase A: per-thread FLOAT min over subset [0, MSUB), self included ----
    float km0 = __builtin_inff(), km1 = km0, km2 = km0, km3 = km0;
    float km4 = km0, km5 = km0, km6 = km0, km7 = km0;

    for (int j = tid; j < MSUB; j += 256) {
        float4 pa = rv4[j * 4 + 0], pb = rv4[j * 4 + 1];
        float4 pc = rv4[j * 4 + 2], pd = rv4[j * 4 + 3];
        float pn = nrm[j];
#define PHA(qi) { \
        float acc = dot16v(q##qi##a, q##qi##b, q##qi##c, q##qi##d, pa, pb, pc, pd); \
        float d2 = fmaxf(fmaf(-2.f, acc, qn##qi + pn), 0.f); \
        km##qi = fminf(km##qi, d2); }
        PHA(0) PHA(1) PHA(2) PHA(3) PHA(4) PHA(5) PHA(6) PHA(7)
    }
    minbuf[0][tid] = km0; minbuf[1][tid] = km1; minbuf[2][tid] = km2; minbuf[3][tid] = km3;
    minbuf[4][tid] = km4; minbuf[5][tid] = km5; minbuf[6][tid] = km6; minbuf[7][tid] = km7;
    __syncthreads();

    // ---- bound: 26 value-extractions from the 256 per-thread mins ----
    // Each extraction retires >=1 distinct point's min; after 26, >=26 distinct
    // points have d2 <= bk => bk >= true 26th-NN d2 (incl self). Valid bound.
    for (int qq = 0; qq < 2; ++qq) {
        int qi = 2 * w + qq;
        float v0 = minbuf[qi][lane];
        float v1 = minbuf[qi][lane + 64];
        float v2 = minbuf[qi][lane + 128];
        float v3 = minbuf[qi][lane + 192];
        float bk = __builtin_inff();
        for (int it = 0; it < KNN + 1; ++it) {
            float m = fminf(fminf(v0, v1), fminf(v2, v3));
#pragma unroll
            for (int off = 32; off >= 1; off >>= 1)
                m = fminf(m, __shfl_xor(m, off, 64));
            bk = m;
            if (v0 == m) v0 = __builtin_inff();
            if (v1 == m) v1 = __builtin_inff();
            if (v2 == m) v2 = __builtin_inff();
            if (v3 == m) v3 = __builtin_inff();
        }
        if (lane == 0) Bv[qi] = bk;
    }
    __syncthreads();

    // bounds are block-uniform -> pin to SGPRs
#define LB(qi) float b##qi = __uint_as_float( \
        (unsigned)__builtin_amdgcn_readfirstlane((int)__float_as_uint(Bv[qi])));
    LB(0) LB(1) LB(2) LB(3) LB(4) LB(5) LB(6) LB(7)

    // ---- phase B: single full pass, collect d2 <= B (self included) ----
    for (int j = tid; j < BN; j += 256) {
        float4 pa = rv4[j * 4 + 0], pb = rv4[j * 4 + 1];
        float4 pc = rv4[j * 4 + 2], pd = rv4[j * 4 + 3];
        float pn = nrm[j];
#define PHB(qi) { \
        float acc = dot16v(q##qi##a, q##qi##b, q##qi##c, q##qi##d, pa, pb, pc, pd); \
        float d2 = fmaxf(fmaf(-2.f, acc, qn##qi + pn), 0.f); \
        if (d2 <= b##qi) { \
            int pos = atomicAdd(&lcnt[qi], 1); \
            if (pos < CAP) { listV[qi][pos] = d2; listI[qi][pos] = j; } } }
        PHB(0) PHB(1) PHB(2) PHB(3) PHB(4) PHB(5) PHB(6) PHB(7)
    }
    __syncthreads();

    // ---- exact 26 extract-mins; iter 0 is self, store iters 1..25 ----
    for (int qq = 0; qq < 2; ++qq) {
        int qi = 2 * w + qq;
        int cnt = lcnt[qi]; if (cnt > CAP) cnt = CAP;
        for (int it = 0; it < KNN + 1; ++it) {
            u64 best = ~0ull;
            for (int e = lane; e < cnt; e += 64) {
                u64 key = (((u64)__float_as_uint(listV[qi][e])) << 32) |
                          (unsigned)listI[qi][e];
                if (key < best) best = key;
            }
            best = wave_min_u64(best);
            int wj = (int)(best & 0xffffffffu);
            for (int e = lane; e < cnt; e += 64)
                if (listI[qi][e] == wj) listV[qi][e] = __builtin_inff();
            if (lane == 0 && it > 0) nbr[qi][it - 1] = wj;
        }
    }
    __syncthreads();   // lists dead; eigen scratch overlays them

    // ---- eigen phase: wave-private scratch, zero barriers ----
    float* ews  = (float*)smem + w * 1280;
    float* pts  = ews;          // 25 x stride 20
    float* Arow = ews + 512;    // 16 x stride 20
    float* Acol = ews + 832;    // 16 x stride 20
    float* vbuf = ews + 1152;   // 16
    float* ubuf = ews + 1168;   // 2 x 16

    const int q4 = (lane >> 4) << 2;
    const int jc = lane & 15;

    for (int rr = 0; rr < 2; ++rr) {
        int qi = 2 * w + rr;
        for (int m = 0; m < 2; ++m) {
            const float4* src4 = (const float4*)((m == 0) ? latent : raw);
            if (lane < KNN) {
                int nb = nbr[qi][lane];
                float4 r0 = src4[nb * 4 + 0], r1 = src4[nb * 4 + 1];
                float4 r2 = src4[nb * 4 + 2], r3 = src4[nb * 4 + 3];
                float4* dst = (float4*)(pts + lane * 20);
                dst[0] = r0; dst[1] = r1; dst[2] = r2; dst[3] = r3;
            }
            // gram + mean adjustment: C = G - s s^T / 25
            float g0 = 0, g1 = 0, g2 = 0, g3 = 0;
            float s0 = 0, s1 = 0, s2 = 0, s3 = 0, sj = 0;
            for (int k = 0; k < KNN; ++k) {
                float4 qv = *(const float4*)(pts + k * 20 + q4);
                float rj = pts[k * 20 + jc];
                g0 = fmaf(qv.x, rj, g0); g1 = fmaf(qv.y, rj, g1);
                g2 = fmaf(qv.z, rj, g2); g3 = fmaf(qv.w, rj, g3);
                s0 += qv.x; s1 += qv.y; s2 += qv.z; s3 += qv.w; sj += rj;
            }
            const float i25 = 1.0f / 25.0f;
            float sjs = sj * i25;
            float a0 = fmaf(-s0, sjs, g0);
            float a1 = fmaf(-s1, sjs, g1);
            float a2 = fmaf(-s2, sjs, g2);
            float a3 = fmaf(-s3, sjs, g3);

            // 5 trace-normalized squarings (register-blocked, dual LDS layout)
            for (int sq = 0; sq < 5; ++sq) {
                Arow[(q4 + 0) * 20 + jc] = a0;
                Arow[(q4 + 1) * 20 + jc] = a1;
                Arow[(q4 + 2) * 20 + jc] = a2;
                Arow[(q4 + 3) * 20 + jc] = a3;
                *(float4*)(Acol + jc * 20 + q4) = make_float4(a0, a1, a2, a3);
                float t = 0.f;
                if (jc == q4 + 0) t += a0;
                if (jc == q4 + 1) t += a1;
                if (jc == q4 + 2) t += a2;
                if (jc == q4 + 3) t += a3;
#pragma unroll
                for (int off = 32; off >= 1; off >>= 1) t += __shfl_xor(t, off, 64);
                float itr = (t > 0.f) ? (1.0f / t) : 1.0f;
                float b0_ = 0, b1_ = 0, b2_ = 0, b3_ = 0;
#pragma unroll
                for (int k = 0; k < DD; ++k) {
                    float4 ck = *(const float4*)(Acol + k * 20 + q4);
                    float rk = Arow[k * 20 + jc];
                    b0_ = fmaf(ck.x, rk, b0_);
                    b1_ = fmaf(ck.y, rk, b1_);
                    b2_ = fmaf(ck.z, rk, b2_);
                    b3_ = fmaf(ck.w, rk, b3_);
                }
                float sc = itr * itr;
                a0 = b0_ * sc; a1 = b1_ * sc; a2 = b2_ * sc; a3 = b3_ * sc;
            }

            // column norms + argmax (tie: lower j)
            float cn = a0 * a0;
            cn = fmaf(a1, a1, cn); cn = fmaf(a2, a2, cn); cn = fmaf(a3, a3, cn);
            cn += __shfl_xor(cn, 16, 64);
            cn += __shfl_xor(cn, 32, 64);
            int bj = jc;
#pragma unroll
            for (int off = 32; off >= 1; off >>= 1) {
                float on = __shfl_xor(cn, off, 64);
                int   oj = __shfl_xor(bj, off, 64);
                if (on > cn || (on == cn && oj < bj)) { cn = on; bj = oj; }
            }

            if (jc == bj) {
                vbuf[q4 + 0] = a0; vbuf[q4 + 1] = a1;
                vbuf[q4 + 2] = a2; vbuf[q4 + 3] = a3;
            }
            float vj = vbuf[jc];
            float w0 = a0 * vj, w1 = a1 * vj, w2 = a2 * vj, w3 = a3 * vj;
#pragma unroll
            for (int off = 1; off < 16; off <<= 1) {
                w0 += __shfl_xor(w0, off, 64);
                w1 += __shfl_xor(w1, off, 64);
                w2 += __shfl_xor(w2, off, 64);
                w3 += __shfl_xor(w3, off, 64);
            }
            if (jc == 0) {
                vbuf[q4 + 0] = w0; vbuf[q4 + 1] = w1;
                vbuf[q4 + 2] = w2; vbuf[q4 + 3] = w3;
            }
            vj = vbuf[jc];
            float x0 = a0 * vj, x1 = a1 * vj, x2 = a2 * vj, x3 = a3 * vj;
#pragma unroll
            for (int off = 1; off < 16; off <<= 1) {
                x0 += __shfl_xor(x0, off, 64);
                x1 += __shfl_xor(x1, off, 64);
                x2 += __shfl_xor(x2, off, 64);
                x3 += __shfl_xor(x3, off, 64);
            }
            float nv = x0 * x0;
            nv = fmaf(x1, x1, nv); nv = fmaf(x2, x2, nv); nv = fmaf(x3, x3, nv);
            nv += __shfl_xor(nv, 16, 64);
            nv += __shfl_xor(nv, 32, 64);
            float inv = rsqrtf(fmaxf(nv, 1e-30f));
            if (jc == 0) {
                ubuf[m * 16 + q4 + 0] = x0 * inv;
                ubuf[m * 16 + q4 + 1] = x1 * inv;
                ubuf[m * 16 + q4 + 2] = x2 * inv;
                ubuf[m * 16 + q4 + 3] = x3 * inv;
            }
        }
        float du = ubuf[jc] * ubuf[16 + jc];
#pragma unroll
        for (int off = 1; off < 16; off <<= 1) du += __shfl_xor(du, off, 64);
        if (lane == 0) tsa[row0 + qi] = 2.0f - 2.0f * du * du;
    }
}

// ---------------- finalize ----------------
__global__ void finalize_kernel(const float* __restrict__ tsa,
                                const float* __restrict__ part,
                                float* __restrict__ out) {
    __shared__ float red[256];
    int tid = threadIdx.x;
    float s = 0.f;
    for (int i = tid; i < BN; i += 256) s += tsa[i];
    red[tid] = s;
    __syncthreads();
    for (int off = 128; off > 0; off >>= 1) {
        if (tid < off) red[tid] += red[tid + off];
        __syncthreads();
    }
    float tsaSum = red[0];
    __syncthreads();
    red[tid] = part[tid];
    __syncthreads();
    for (int off = 128; off > 0; off >>= 1) {
        if (tid < off) red[tid] += red[tid + off];
        __syncthreads();
    }
    if (tid == 0)
        out[0] = red[0] * (1.0f / (float)(BN * DD)) + 0.1f * (tsaSum * (1.0f / (float)BN));
}

extern "C" void kernel_launch(void* const* d_in, const int* in_sizes, int n_in,
                              void* d_out, int out_size, void* d_ws, size_t ws_size,
                              hipStream_t stream) {
    const float* outputs = (const float*)d_in[0];
    const float* targets = (const float*)d_in[1];
    const float* latent  = (const float*)d_in[2];
    const float* raw     = (const float*)d_in[3];
    float* ws_f = (float*)d_ws;
    float* tsa  = ws_f;            // BN
    float* part = ws_f + BN;       // 256
    float* nrm  = ws_f + BN + 256; // BN

    norms_kernel<<<BN / 256, 256, 0, stream>>>(raw, nrm);
    recon_kernel<<<256, 256, 0, stream>>>(outputs, targets, part);
    tsa_kernel<<<BN / QB, 256, 0, stream>>>(latent, raw, nrm, tsa);
    finalize_kernel<<<1, 256, 0, stream>>>(tsa, part, (float*)d_out);
}

// Round 11
// 335.455 us; speedup vs baseline: 1.6666x; 1.6666x over previous
//
#include <hip/hip_runtime.h>

#define BN 16384
#define DD 16
#define KNN 25
#define QB 16
#define MSUB 4096
#define CAP 192

typedef unsigned long long u64;
typedef __attribute__((ext_vector_type(8))) short bf16x8;
typedef __attribute__((ext_vector_type(4))) float f32x4;

__device__ __forceinline__ u64 wave_min_u64(u64 v) {
#pragma unroll
    for (int off = 32; off >= 1; off >>= 1) {
        unsigned lo = (unsigned)v, hi = (unsigned)(v >> 32);
        unsigned olo = __shfl_xor(lo, off, 64);
        unsigned ohi = __shfl_xor(hi, off, 64);
        u64 o = (((u64)ohi) << 32) | olo;
        if (o < v) v = o;
    }
    return v;
}

__device__ __forceinline__ unsigned short f2bf(float f) {
    unsigned u = __float_as_uint(f);
    unsigned r = (u + 0x7FFFu + ((u >> 16) & 1u)) >> 16;   // RNE
    return (unsigned short)r;
}

// ---------------- prep: norms + split-precision bf16 [hi(16)|lo(16)] ----------------
__global__ void prep_kernel(const float* __restrict__ raw, uint4* __restrict__ rawhl,
                            float* __restrict__ nrm) {
    int j = blockIdx.x * 256 + threadIdx.x;
    if (j >= BN) return;
    const float4* rv = (const float4*)raw + j * 4;
    float4 a = rv[0], b = rv[1], c = rv[2], d = rv[3];
    float x[16] = {a.x,a.y,a.z,a.w,b.x,b.y,b.z,b.w,c.x,c.y,c.z,c.w,d.x,d.y,d.z,d.w};
    float s = 0.f;
#pragma unroll
    for (int i = 0; i < 16; ++i) s = fmaf(x[i], x[i], s);
    nrm[j] = s;
    unsigned hp[8], lp[8];
#pragma unroll
    for (int i = 0; i < 8; ++i) {
        unsigned short h0 = f2bf(x[2*i]), h1 = f2bf(x[2*i+1]);
        float f0 = __uint_as_float(((unsigned)h0) << 16);
        float f1 = __uint_as_float(((unsigned)h1) << 16);
        unsigned short l0 = f2bf(x[2*i] - f0), l1 = f2bf(x[2*i+1] - f1);
        hp[i] = (unsigned)h0 | ((unsigned)h1 << 16);
        lp[i] = (unsigned)l0 | ((unsigned)l1 << 16);
    }
    uint4* dst = rawhl + j * 4;
    dst[0] = make_uint4(hp[0], hp[1], hp[2], hp[3]);   // hi dims 0-7
    dst[1] = make_uint4(hp[4], hp[5], hp[6], hp[7]);   // hi dims 8-15
    dst[2] = make_uint4(lp[0], lp[1], lp[2], lp[3]);   // lo dims 0-7
    dst[3] = make_uint4(lp[4], lp[5], lp[6], lp[7]);   // lo dims 8-15
}

// ---------------- recon partials ----------------
__global__ void recon_kernel(const float* __restrict__ o, const float* __restrict__ t,
                             float* __restrict__ part) {
    __shared__ float red[256];
    int tid = threadIdx.x;
    int idx = blockIdx.x * 256 + tid;
    float s = 0.f;
    for (int i = idx; i < BN * DD; i += 256 * 256) {
        float d = o[i] - t[i];
        s = fmaf(d, d, s);
    }
    red[tid] = s;
    __syncthreads();
    for (int off = 128; off > 0; off >>= 1) {
        if (tid < off) red[tid] += red[tid + off];
        __syncthreads();
    }
    if (tid == 0) part[blockIdx.x] = red[0];
}

// ---------------- main: 16 rows per block, MFMA distance engine ----------------
__global__ __launch_bounds__(256, 4) void tsa_kernel(const float* __restrict__ latent,
                                                     const float* __restrict__ raw,
                                                     const uint4* __restrict__ rawhl,
                                                     const float* __restrict__ nrm,
                                                     float* __restrict__ tsa) {
    const int tid  = threadIdx.x;
    const int lane = tid & 63;
    const int w    = tid >> 6;
    const int l15  = lane & 15;
    const int g    = lane >> 4;
    const int row0 = blockIdx.x * QB;

    // 24.6 KB overlay: phase A = minbuf[16][64], phase B/select = lists,
    // eigen = per-wave scratch (4 x 5 KB)
    __shared__ __align__(16) char smem[QB * CAP * 8];
    float (*listV)[CAP] = (float (*)[CAP])smem;
    int   (*listI)[CAP] = (int (*)[CAP])(smem + QB * CAP * 4);
    float (*minbuf)[64] = (float (*)[64])smem;

    __shared__ int   lcnt[QB];
    __shared__ float Bv[QB];
    __shared__ int   nbr[QB][KNN];

    if (tid < QB) lcnt[tid] = 0;

    const bf16x8* rb = (const bf16x8*)rawhl;

    // A-fragments: A[row=l15][k=8g..8g+7]; A1 = [q_hi | q_hi], A2 = [q_lo | q_lo]
    bf16x8 A1 = rb[(row0 + l15) * 4 + (g & 1)];
    bf16x8 A2 = rb[(row0 + l15) * 4 + 2 + (g & 1)];

    // qn for the 4 C-rows (row = g*4 + r) this lane covers
    float4 vqn = *(const float4*)(nrm + row0 + g * 4);

    // ---- phase A: per-tracker min over points [0, MSUB) ----
    const float INFf = __builtin_inff();
    float mn0 = INFf, mn1 = INFf, mn2 = INFf, mn3 = INFf;
    for (int t = w; t < MSUB / 16; t += 4) {
        int pt = t * 16 + l15;
        bf16x8 Bf = rb[pt * 4 + g];       // B[k=8g..][col=l15]
        float pn = nrm[pt];
        f32x4 c = {0.f, 0.f, 0.f, 0.f};
        c = __builtin_amdgcn_mfma_f32_16x16x32_bf16(A1, Bf, c, 0, 0, 0);
        c = __builtin_amdgcn_mfma_f32_16x16x32_bf16(A2, Bf, c, 0, 0, 0);
        mn0 = fminf(mn0, fmaxf(fmaf(-2.f, c[0], vqn.x + pn), 0.f));
        mn1 = fminf(mn1, fmaxf(fmaf(-2.f, c[1], vqn.y + pn), 0.f));
        mn2 = fminf(mn2, fmaxf(fmaf(-2.f, c[2], vqn.z + pn), 0.f));
        mn3 = fminf(mn3, fmaxf(fmaf(-2.f, c[3], vqn.w + pn), 0.f));
    }
    minbuf[g * 4 + 0][w * 16 + l15] = mn0;
    minbuf[g * 4 + 1][w * 16 + l15] = mn1;
    minbuf[g * 4 + 2][w * 16 + l15] = mn2;
    minbuf[g * 4 + 3][w * 16 + l15] = mn3;
    __syncthreads();

    // ---- bound: 26 value-extractions from 64 trackers/row; wave w rows 4w..4w+3 ----
    for (int rr = 0; rr < 4; ++rr) {
        int row = 4 * w + rr;
        float v = minbuf[row][lane];
        float bk = INFf;
        for (int it = 0; it < KNN + 1; ++it) {
            float m = v;
#pragma unroll
            for (int off = 32; off >= 1; off >>= 1)
                m = fminf(m, __shfl_xor(m, off, 64));
            bk = m;
            if (v == m) v = INFf;
        }
        if (lane == 0) Bv[row] = bk;
    }
    __syncthreads();

    float4 vb;
    vb.x = Bv[g * 4 + 0]; vb.y = Bv[g * 4 + 1];
    vb.z = Bv[g * 4 + 2]; vb.w = Bv[g * 4 + 3];

    // ---- phase B: full pass, collect d2 <= bound (self included) ----
    for (int t = w; t < BN / 16; t += 4) {
        int pt = t * 16 + l15;
        bf16x8 Bf = rb[pt * 4 + g];
        float pn = nrm[pt];
        f32x4 c = {0.f, 0.f, 0.f, 0.f};
        c = __builtin_amdgcn_mfma_f32_16x16x32_bf16(A1, Bf, c, 0, 0, 0);
        c = __builtin_amdgcn_mfma_f32_16x16x32_bf16(A2, Bf, c, 0, 0, 0);
#define COLL(r, QN, BB) { \
        float d2 = fmaxf(fmaf(-2.f, c[r], QN + pn), 0.f); \
        if (d2 <= BB) { \
            int q = g * 4 + r; \
            int pos = atomicAdd(&lcnt[q], 1); \
            if (pos < CAP) { listV[q][pos] = d2; listI[q][pos] = pt; } } }
        COLL(0, vqn.x, vb.x) COLL(1, vqn.y, vb.y)
        COLL(2, vqn.z, vb.z) COLL(3, vqn.w, vb.w)
#undef COLL
    }
    __syncthreads();

    // ---- exact 26 extract-mins on approx metric; iter 0 = self ----
    for (int rr = 0; rr < 4; ++rr) {
        int qi = 4 * w + rr;
        int cnt = lcnt[qi]; if (cnt > CAP) cnt = CAP;
        for (int it = 0; it < KNN + 1; ++it) {
            u64 best = ~0ull;
            for (int e = lane; e < cnt; e += 64) {
                u64 key = (((u64)__float_as_uint(listV[qi][e])) << 32) |
                          (unsigned)listI[qi][e];
                if (key < best) best = key;
            }
            best = wave_min_u64(best);
            int wj = (int)(best & 0xffffffffu);
            for (int e = lane; e < cnt; e += 64)
                if (listI[qi][e] == wj) listV[qi][e] = INFf;
            if (lane == 0 && it > 0) nbr[qi][it - 1] = wj;
        }
    }
    __syncthreads();   // lists dead; eigen scratch overlays them

    // ---- eigen phase: wave-private scratch, zero barriers; wave w rows 4w..4w+3 ----
    float* ews  = (float*)smem + w * 1280;
    float* pts  = ews;          // 25 x stride 20
    float* Arow = ews + 512;    // 16 x stride 20
    float* Acol = ews + 832;    // 16 x stride 20
    float* vbuf = ews + 1152;   // 16
    float* ubuf = ews + 1168;   // 2 x 16

    const int q4 = g << 2;
    const int jc = l15;

    for (int rr = 0; rr < 4; ++rr) {
        int qi = 4 * w + rr;
        for (int m = 0; m < 2; ++m) {
            const float4* src4 = (const float4*)((m == 0) ? latent : raw);
            if (lane < KNN) {
                int nb = nbr[qi][lane];
                float4 r0 = src4[nb * 4 + 0], r1 = src4[nb * 4 + 1];
                float4 r2 = src4[nb * 4 + 2], r3 = src4[nb * 4 + 3];
                float4* dst = (float4*)(pts + lane * 20);
                dst[0] = r0; dst[1] = r1; dst[2] = r2; dst[3] = r3;
            }
            // gram + mean adjustment: C = G - s s^T / 25
            float g0 = 0, g1 = 0, g2 = 0, g3 = 0;
            float s0 = 0, s1 = 0, s2 = 0, s3 = 0, sj = 0;
            for (int k = 0; k < KNN; ++k) {
                float4 qv = *(const float4*)(pts + k * 20 + q4);
                float rj = pts[k * 20 + jc];
                g0 = fmaf(qv.x, rj, g0); g1 = fmaf(qv.y, rj, g1);
                g2 = fmaf(qv.z, rj, g2); g3 = fmaf(qv.w, rj, g3);
                s0 += qv.x; s1 += qv.y; s2 += qv.z; s3 += qv.w; sj += rj;
            }
            const float i25 = 1.0f / 25.0f;
            float sjs = sj * i25;
            float a0 = fmaf(-s0, sjs, g0);
            float a1 = fmaf(-s1, sjs, g1);
            float a2 = fmaf(-s2, sjs, g2);
            float a3 = fmaf(-s3, sjs, g3);

            // 5 trace-normalized squarings (register-blocked, dual LDS layout)
            for (int sq = 0; sq < 5; ++sq) {
                Arow[(q4 + 0) * 20 + jc] = a0;
                Arow[(q4 + 1) * 20 + jc] = a1;
                Arow[(q4 + 2) * 20 + jc] = a2;
                Arow[(q4 + 3) * 20 + jc] = a3;
                *(float4*)(Acol + jc * 20 + q4) = make_float4(a0, a1, a2, a3);
                float t = 0.f;
                if (jc == q4 + 0) t += a0;
                if (jc == q4 + 1) t += a1;
                if (jc == q4 + 2) t += a2;
                if (jc == q4 + 3) t += a3;
#pragma unroll
                for (int off = 32; off >= 1; off >>= 1) t += __shfl_xor(t, off, 64);
                float itr = (t > 0.f) ? (1.0f / t) : 1.0f;
                float b0_ = 0, b1_ = 0, b2_ = 0, b3_ = 0;
#pragma unroll
                for (int k = 0; k < DD; ++k) {
                    float4 ck = *(const float4*)(Acol + k * 20 + q4);
                    float rk = Arow[k * 20 + jc];
                    b0_ = fmaf(ck.x, rk, b0_);
                    b1_ = fmaf(ck.y, rk, b1_);
                    b2_ = fmaf(ck.z, rk, b2_);
                    b3_ = fmaf(ck.w, rk, b3_);
                }
                float sc = itr * itr;
                a0 = b0_ * sc; a1 = b1_ * sc; a2 = b2_ * sc; a3 = b3_ * sc;
            }

            // column norms + argmax (tie: lower j)
            float cn = a0 * a0;
            cn = fmaf(a1, a1, cn); cn = fmaf(a2, a2, cn); cn = fmaf(a3, a3, cn);
            cn += __shfl_xor(cn, 16, 64);
            cn += __shfl_xor(cn, 32, 64);
            int bj = jc;
#pragma unroll
            for (int off = 32; off >= 1; off >>= 1) {
                float on = __shfl_xor(cn, off, 64);
                int   oj = __shfl_xor(bj, off, 64);
                if (on > cn || (on == cn && oj < bj)) { cn = on; bj = oj; }
            }

            if (jc == bj) {
                vbuf[q4 + 0] = a0; vbuf[q4 + 1] = a1;
                vbuf[q4 + 2] = a2; vbuf[q4 + 3] = a3;
            }
            float vj = vbuf[jc];
            float w0 = a0 * vj, w1 = a1 * vj, w2 = a2 * vj, w3 = a3 * vj;
#pragma unroll
            for (int off = 1; off < 16; off <<= 1) {
                w0 += __shfl_xor(w0, off, 64);
                w1 += __shfl_xor(w1, off, 64);
                w2 += __shfl_xor(w2, off, 64);
                w3 += __shfl_xor(w3, off, 64);
            }
            if (jc == 0) {
                vbuf[q4 + 0] = w0; vbuf[q4 + 1] = w1;
                vbuf[q4 + 2] = w2; vbuf[q4 + 3] = w3;
            }
            vj = vbuf[jc];
            float x0 = a0 * vj, x1 = a1 * vj, x2 = a2 * vj, x3 = a3 * vj;
#pragma unroll
            for (int off = 1; off < 16; off <<= 1) {
                x0 += __shfl_xor(x0, off, 64);
                x1 += __shfl_xor(x1, off, 64);
                x2 += __shfl_xor(x2, off, 64);
                x3 += __shfl_xor(x3, off, 64);
            }
            float nv = x0 * x0;
            nv = fmaf(x1, x1, nv); nv = fmaf(x2, x2, nv); nv = fmaf(x3, x3, nv);
            nv += __shfl_xor(nv, 16, 64);
            nv += __shfl_xor(nv, 32, 64);
            float inv = rsqrtf(fmaxf(nv, 1e-30f));
            if (jc == 0) {
                ubuf[m * 16 + q4 + 0] = x0 * inv;
                ubuf[m * 16 + q4 + 1] = x1 * inv;
                ubuf[m * 16 + q4 + 2] = x2 * inv;
                ubuf[m * 16 + q4 + 3] = x3 * inv;
            }
        }
        float du = ubuf[jc] * ubuf[16 + jc];
#pragma unroll
        for (int off = 1; off < 16; off <<= 1) du += __shfl_xor(du, off, 64);
        if (lane == 0) tsa[row0 + qi] = 2.0f - 2.0f * du * du;
    }
}

// ---------------- finalize ----------------
__global__ void finalize_kernel(const float* __restrict__ tsa,
                                const float* __restrict__ part,
                                float* __restrict__ out) {
    __shared__ float red[256];
    int tid = threadIdx.x;
    float s = 0.f;
    for (int i = tid; i < BN; i += 256) s += tsa[i];
    red[tid] = s;
    __syncthreads();
    for (int off = 128; off > 0; off >>= 1) {
        if (tid < off) red[tid] += red[tid + off];
        __syncthreads();
    }
    float tsaSum = red[0];
    __syncthreads();
    red[tid] = part[tid];
    __syncthreads();
    for (int off = 128; off > 0; off >>= 1) {
        if (tid < off) red[tid] += red[tid + off];
        __syncthreads();
    }
    if (tid == 0)
        out[0] = red[0] * (1.0f / (float)(BN * DD)) + 0.1f * (tsaSum * (1.0f / (float)BN));
}

extern "C" void kernel_launch(void* const* d_in, const int* in_sizes, int n_in,
                              void* d_out, int out_size, void* d_ws, size_t ws_size,
                              hipStream_t stream) {
    const float* outputs = (const float*)d_in[0];
    const float* targets = (const float*)d_in[1];
    const float* latent  = (const float*)d_in[2];
    const float* raw     = (const float*)d_in[3];
    float* ws_f = (float*)d_ws;
    float* tsa  = ws_f;                         // BN floats
    float* part = ws_f + BN;                    // 256
    float* nrm  = ws_f + BN + 256;              // BN
    uint4* rawhl = (uint4*)(ws_f + 2 * BN + 256); // BN*64 bytes (16B-aligned offset)

    prep_kernel<<<BN / 256, 256, 0, stream>>>(raw, rawhl, nrm);
    recon_kernel<<<256, 256, 0, stream>>>(outputs, targets, part);
    tsa_kernel<<<BN / QB, 256, 0, stream>>>(latent, raw, rawhl, nrm, tsa);
    finalize_kernel<<<1, 256, 0, stream>>>(tsa, part, (float*)d_out);
}

// Round 12
// 331.287 us; speedup vs baseline: 1.6876x; 1.0126x over previous
//
#include <hip/hip_runtime.h>

#define BN 16384
#define DD 16
#define KNN 25
#define QB 16
#define MSUB 4096
#define CAP 192
#define NSQ 4

typedef unsigned long long u64;
typedef __attribute__((ext_vector_type(8))) short bf16x8;
typedef __attribute__((ext_vector_type(4))) float f32x4;

__device__ __forceinline__ u64 wave_min_u64(u64 v) {
#pragma unroll
    for (int off = 32; off >= 1; off >>= 1) {
        unsigned lo = (unsigned)v, hi = (unsigned)(v >> 32);
        unsigned olo = __shfl_xor(lo, off, 64);
        unsigned ohi = __shfl_xor(hi, off, 64);
        u64 o = (((u64)ohi) << 32) | olo;
        if (o < v) v = o;
    }
    return v;
}

__device__ __forceinline__ unsigned short f2bf(float f) {
    unsigned u = __float_as_uint(f);
    unsigned r = (u + 0x7FFFu + ((u >> 16) & 1u)) >> 16;   // RNE
    return (unsigned short)r;
}

// ---------------- prep: norms + split-precision bf16 [hi(16)|lo(16)] ----------------
__global__ void prep_kernel(const float* __restrict__ raw, uint4* __restrict__ rawhl,
                            float* __restrict__ nrm) {
    int j = blockIdx.x * 256 + threadIdx.x;
    if (j >= BN) return;
    const float4* rv = (const float4*)raw + j * 4;
    float4 a = rv[0], b = rv[1], c = rv[2], d = rv[3];
    float x[16] = {a.x,a.y,a.z,a.w,b.x,b.y,b.z,b.w,c.x,c.y,c.z,c.w,d.x,d.y,d.z,d.w};
    float s = 0.f;
#pragma unroll
    for (int i = 0; i < 16; ++i) s = fmaf(x[i], x[i], s);
    nrm[j] = s;
    unsigned hp[8], lp[8];
#pragma unroll
    for (int i = 0; i < 8; ++i) {
        unsigned short h0 = f2bf(x[2*i]), h1 = f2bf(x[2*i+1]);
        float f0 = __uint_as_float(((unsigned)h0) << 16);
        float f1 = __uint_as_float(((unsigned)h1) << 16);
        unsigned short l0 = f2bf(x[2*i] - f0), l1 = f2bf(x[2*i+1] - f1);
        hp[i] = (unsigned)h0 | ((unsigned)h1 << 16);
        lp[i] = (unsigned)l0 | ((unsigned)l1 << 16);
    }
    uint4* dst = rawhl + j * 4;
    dst[0] = make_uint4(hp[0], hp[1], hp[2], hp[3]);   // hi dims 0-7
    dst[1] = make_uint4(hp[4], hp[5], hp[6], hp[7]);   // hi dims 8-15
    dst[2] = make_uint4(lp[0], lp[1], lp[2], lp[3]);   // lo dims 0-7
    dst[3] = make_uint4(lp[4], lp[5], lp[6], lp[7]);   // lo dims 8-15
}

// ---------------- recon partials ----------------
__global__ void recon_kernel(const float* __restrict__ o, const float* __restrict__ t,
                             float* __restrict__ part) {
    __shared__ float red[256];
    int tid = threadIdx.x;
    int idx = blockIdx.x * 256 + tid;
    float s = 0.f;
    for (int i = idx; i < BN * DD; i += 256 * 256) {
        float d = o[i] - t[i];
        s = fmaf(d, d, s);
    }
    red[tid] = s;
    __syncthreads();
    for (int off = 128; off > 0; off >>= 1) {
        if (tid < off) red[tid] += red[tid + off];
        __syncthreads();
    }
    if (tid == 0) part[blockIdx.x] = red[0];
}

// ---------------- main: 16 rows per block, MFMA distance engine ----------------
__global__ __launch_bounds__(256, 6) void tsa_kernel(const float* __restrict__ latent,
                                                     const float* __restrict__ raw,
                                                     const uint4* __restrict__ rawhl,
                                                     const float* __restrict__ nrm,
                                                     float* __restrict__ tsa) {
    const int tid  = threadIdx.x;
    const int lane = tid & 63;
    const int w    = tid >> 6;
    const int l15  = lane & 15;
    const int g    = lane >> 4;
    const int row0 = blockIdx.x * QB;

    // 24.6 KB overlay: phase A = minbuf[16][64], phase B/select = lists,
    // eigen = per-wave scratch (4 x 5 KB)
    __shared__ __align__(16) char smem[QB * CAP * 8];
    float (*listV)[CAP] = (float (*)[CAP])smem;
    int   (*listI)[CAP] = (int (*)[CAP])(smem + QB * CAP * 4);
    float (*minbuf)[64] = (float (*)[64])smem;

    __shared__ int   lcnt[QB];
    __shared__ float Bv[QB];
    __shared__ int   nbr[QB][KNN];

    if (tid < QB) lcnt[tid] = 0;

    const bf16x8* rb = (const bf16x8*)rawhl;

    // A-fragments: A[row=l15][k=8g..8g+7]; A1 = [q_hi | q_hi], A2 = [q_lo | q_lo]
    bf16x8 A1 = rb[(row0 + l15) * 4 + (g & 1)];
    bf16x8 A2 = rb[(row0 + l15) * 4 + 2 + (g & 1)];

    // qn for the 4 C-rows (row = g*4 + r) this lane covers
    float4 vqn = *(const float4*)(nrm + row0 + g * 4);

    // ---- phase A: per-tracker min over points [0, MSUB) ----
    const float INFf = __builtin_inff();
    float mn0 = INFf, mn1 = INFf, mn2 = INFf, mn3 = INFf;
    for (int t = w; t < MSUB / 16; t += 4) {
        int pt = t * 16 + l15;
        bf16x8 Bf = rb[pt * 4 + g];       // B[k=8g..][col=l15]
        float pn = nrm[pt];
        f32x4 c = {0.f, 0.f, 0.f, 0.f};
        c = __builtin_amdgcn_mfma_f32_16x16x32_bf16(A1, Bf, c, 0, 0, 0);
        c = __builtin_amdgcn_mfma_f32_16x16x32_bf16(A2, Bf, c, 0, 0, 0);
        mn0 = fminf(mn0, fmaxf(fmaf(-2.f, c[0], vqn.x + pn), 0.f));
        mn1 = fminf(mn1, fmaxf(fmaf(-2.f, c[1], vqn.y + pn), 0.f));
        mn2 = fminf(mn2, fmaxf(fmaf(-2.f, c[2], vqn.z + pn), 0.f));
        mn3 = fminf(mn3, fmaxf(fmaf(-2.f, c[3], vqn.w + pn), 0.f));
    }
    minbuf[g * 4 + 0][w * 16 + l15] = mn0;
    minbuf[g * 4 + 1][w * 16 + l15] = mn1;
    minbuf[g * 4 + 2][w * 16 + l15] = mn2;
    minbuf[g * 4 + 3][w * 16 + l15] = mn3;
    __syncthreads();

    // ---- bound: 26 value-extractions from 64 trackers/row; wave w rows 4w..4w+3 ----
    for (int rr = 0; rr < 4; ++rr) {
        int row = 4 * w + rr;
        float v = minbuf[row][lane];
        float bk = INFf;
        for (int it = 0; it < KNN + 1; ++it) {
            float m = v;
#pragma unroll
            for (int off = 32; off >= 1; off >>= 1)
                m = fminf(m, __shfl_xor(m, off, 64));
            bk = m;
            if (v == m) v = INFf;
        }
        if (lane == 0) Bv[row] = bk;
    }
    __syncthreads();

    float4 vb;
    vb.x = Bv[g * 4 + 0]; vb.y = Bv[g * 4 + 1];
    vb.z = Bv[g * 4 + 2]; vb.w = Bv[g * 4 + 3];

    // ---- phase B: full pass, collect d2 <= bound (self included) ----
    for (int t = w; t < BN / 16; t += 4) {
        int pt = t * 16 + l15;
        bf16x8 Bf = rb[pt * 4 + g];
        float pn = nrm[pt];
        f32x4 c = {0.f, 0.f, 0.f, 0.f};
        c = __builtin_amdgcn_mfma_f32_16x16x32_bf16(A1, Bf, c, 0, 0, 0);
        c = __builtin_amdgcn_mfma_f32_16x16x32_bf16(A2, Bf, c, 0, 0, 0);
#define COLL(r, QN, BB) { \
        float d2 = fmaxf(fmaf(-2.f, c[r], QN + pn), 0.f); \
        if (d2 <= BB) { \
            int q = g * 4 + r; \
            int pos = atomicAdd(&lcnt[q], 1); \
            if (pos < CAP) { listV[q][pos] = d2; listI[q][pos] = pt; } } }
        COLL(0, vqn.x, vb.x) COLL(1, vqn.y, vb.y)
        COLL(2, vqn.z, vb.z) COLL(3, vqn.w, vb.w)
#undef COLL
    }
    __syncthreads();

    // ---- exact 26 extract-mins on approx metric; iter 0 = self ----
    for (int rr = 0; rr < 4; ++rr) {
        int qi = 4 * w + rr;
        int cnt = lcnt[qi]; if (cnt > CAP) cnt = CAP;
        for (int it = 0; it < KNN + 1; ++it) {
            u64 best = ~0ull;
            for (int e = lane; e < cnt; e += 64) {
                u64 key = (((u64)__float_as_uint(listV[qi][e])) << 32) |
                          (unsigned)listI[qi][e];
                if (key < best) best = key;
            }
            best = wave_min_u64(best);
            int wj = (int)(best & 0xffffffffu);
            for (int e = lane; e < cnt; e += 64)
                if (listI[qi][e] == wj) listV[qi][e] = INFf;
            if (lane == 0 && it > 0) nbr[qi][it - 1] = wj;
        }
    }
    __syncthreads();   // lists dead; eigen scratch overlays them

    // ---- eigen phase: wave-private scratch, zero barriers; wave w rows 4w..4w+3 ----
    float* ews  = (float*)smem + w * 1280;
    float* pts  = ews;          // 25 x stride 20
    float* Arow = ews + 512;    // 16 x stride 20
    float* Acol = ews + 832;    // 16 x stride 20
    float* vbuf = ews + 1152;   // 16
    float* ubuf = ews + 1168;   // 2 x 16

    const int q4 = g << 2;
    const int jc = l15;

    for (int rr = 0; rr < 4; ++rr) {
        int qi = 4 * w + rr;
        for (int m = 0; m < 2; ++m) {
            const float4* src4 = (const float4*)((m == 0) ? latent : raw);
            if (lane < KNN) {
                int nb = nbr[qi][lane];
                float4 r0 = src4[nb * 4 + 0], r1 = src4[nb * 4 + 1];
                float4 r2 = src4[nb * 4 + 2], r3 = src4[nb * 4 + 3];
                float4* dst = (float4*)(pts + lane * 20);
                dst[0] = r0; dst[1] = r1; dst[2] = r2; dst[3] = r3;
            }
            // gram + mean adjustment: C = G - s s^T / 25
            float g0 = 0, g1 = 0, g2 = 0, g3 = 0;
            float s0 = 0, s1 = 0, s2 = 0, s3 = 0, sj = 0;
            for (int k = 0; k < KNN; ++k) {
                float4 qv = *(const float4*)(pts + k * 20 + q4);
                float rj = pts[k * 20 + jc];
                g0 = fmaf(qv.x, rj, g0); g1 = fmaf(qv.y, rj, g1);
                g2 = fmaf(qv.z, rj, g2); g3 = fmaf(qv.w, rj, g3);
                s0 += qv.x; s1 += qv.y; s2 += qv.z; s3 += qv.w; sj += rj;
            }
            const float i25 = 1.0f / 25.0f;
            float sjs = sj * i25;
            float a0 = fmaf(-s0, sjs, g0);
            float a1 = fmaf(-s1, sjs, g1);
            float a2 = fmaf(-s2, sjs, g2);
            float a3 = fmaf(-s3, sjs, g3);

            // NSQ trace-normalized squarings (register-blocked, dual LDS layout)
            for (int sq = 0; sq < NSQ; ++sq) {
                Arow[(q4 + 0) * 20 + jc] = a0;
                Arow[(q4 + 1) * 20 + jc] = a1;
                Arow[(q4 + 2) * 20 + jc] = a2;
                Arow[(q4 + 3) * 20 + jc] = a3;
                *(float4*)(Acol + jc * 20 + q4) = make_float4(a0, a1, a2, a3);
                float t = 0.f;
                if (jc == q4 + 0) t += a0;
                if (jc == q4 + 1) t += a1;
                if (jc == q4 + 2) t += a2;
                if (jc == q4 + 3) t += a3;
#pragma unroll
                for (int off = 32; off >= 1; off >>= 1) t += __shfl_xor(t, off, 64);
                float itr = (t > 0.f) ? (1.0f / t) : 1.0f;
                float b0_ = 0, b1_ = 0, b2_ = 0, b3_ = 0;
#pragma unroll
                for (int k = 0; k < DD; ++k) {
                    float4 ck = *(const float4*)(Acol + k * 20 + q4);
                    float rk = Arow[k * 20 + jc];
                    b0_ = fmaf(ck.x, rk, b0_);
                    b1_ = fmaf(ck.y, rk, b1_);
                    b2_ = fmaf(ck.z, rk, b2_);
                    b3_ = fmaf(ck.w, rk, b3_);
                }
                float sc = itr * itr;
                a0 = b0_ * sc; a1 = b1_ * sc; a2 = b2_ * sc; a3 = b3_ * sc;
            }

            // column norms + argmax (tie: lower j)
            float cn = a0 * a0;
            cn = fmaf(a1, a1, cn); cn = fmaf(a2, a2, cn); cn = fmaf(a3, a3, cn);
            cn += __shfl_xor(cn, 16, 64);
            cn += __shfl_xor(cn, 32, 64);
            int bj = jc;
#pragma unroll
            for (int off = 32; off >= 1; off >>= 1) {
                float on = __shfl_xor(cn, off, 64);
                int   oj = __shfl_xor(bj, off, 64);
                if (on > cn || (on == cn && oj < bj)) { cn = on; bj = oj; }
            }

            if (jc == bj) {
                vbuf[q4 + 0] = a0; vbuf[q4 + 1] = a1;
                vbuf[q4 + 2] = a2; vbuf[q4 + 3] = a3;
            }
            float vj = vbuf[jc];
            float w0 = a0 * vj, w1 = a1 * vj, w2 = a2 * vj, w3 = a3 * vj;
#pragma unroll
            for (int off = 1; off < 16; off <<= 1) {
                w0 += __shfl_xor(w0, off, 64);
                w1 += __shfl_xor(w1, off, 64);
                w2 += __shfl_xor(w2, off, 64);
                w3 += __shfl_xor(w3, off, 64);
            }
            if (jc == 0) {
                vbuf[q4 + 0] = w0; vbuf[q4 + 1] = w1;
                vbuf[q4 + 2] = w2; vbuf[q4 + 3] = w3;
            }
            vj = vbuf[jc];
            float x0 = a0 * vj, x1 = a1 * vj, x2 = a2 * vj, x3 = a3 * vj;
#pragma unroll
            for (int off = 1; off < 16; off <<= 1) {
                x0 += __shfl_xor(x0, off, 64);
                x1 += __shfl_xor(x1, off, 64);
                x2 += __shfl_xor(x2, off, 64);
                x3 += __shfl_xor(x3, off, 64);
            }
            float nv = x0 * x0;
            nv = fmaf(x1, x1, nv); nv = fmaf(x2, x2, nv); nv = fmaf(x3, x3, nv);
            nv += __shfl_xor(nv, 16, 64);
            nv += __shfl_xor(nv, 32, 64);
            float inv = rsqrtf(fmaxf(nv, 1e-30f));
            if (jc == 0) {
                ubuf[m * 16 + q4 + 0] = x0 * inv;
                ubuf[m * 16 + q4 + 1] = x1 * inv;
                ubuf[m * 16 + q4 + 2] = x2 * inv;
                ubuf[m * 16 + q4 + 3] = x3 * inv;
            }
        }
        float du = ubuf[jc] * ubuf[16 + jc];
#pragma unroll
        for (int off = 1; off < 16; off <<= 1) du += __shfl_xor(du, off, 64);
        if (lane == 0) tsa[row0 + qi] = 2.0f - 2.0f * du * du;
    }
}

// ---------------- finalize ----------------
__global__ void finalize_kernel(const float* __restrict__ tsa,
                                const float* __restrict__ part,
                                float* __restrict__ out) {
    __shared__ float red[256];
    int tid = threadIdx.x;
    float s = 0.f;
    for (int i = tid; i < BN; i += 256) s += tsa[i];
    red[tid] = s;
    __syncthreads();
    for (int off = 128; off > 0; off >>= 1) {
        if (tid < off) red[tid] += red[tid + off];
        __syncthreads();
    }
    float tsaSum = red[0];
    __syncthreads();
    red[tid] = part[tid];
    __syncthreads();
    for (int off = 128; off > 0; off >>= 1) {
        if (tid < off) red[tid] += red[tid + off];
        __syncthreads();
    }
    if (tid == 0)
        out[0] = red[0] * (1.0f / (float)(BN * DD)) + 0.1f * (tsaSum * (1.0f / (float)BN));
}

extern "C" void kernel_launch(void* const* d_in, const int* in_sizes, int n_in,
                              void* d_out, int out_size, void* d_ws, size_t ws_size,
                              hipStream_t stream) {
    const float* outputs = (const float*)d_in[0];
    const float* targets = (const float*)d_in[1];
    const float* latent  = (const float*)d_in[2];
    const float* raw     = (const float*)d_in[3];
    float* ws_f = (float*)d_ws;
    float* tsa  = ws_f;                         // BN floats
    float* part = ws_f + BN;                    // 256
    float* nrm  = ws_f + BN + 256;              // BN
    uint4* rawhl = (uint4*)(ws_f + 2 * BN + 256); // BN*64 bytes (16B-aligned offset)

    prep_kernel<<<BN / 256, 256, 0, stream>>>(raw, rawhl, nrm);
    recon_kernel<<<256, 256, 0, stream>>>(outputs, targets, part);
    tsa_kernel<<<BN / QB, 256, 0, stream>>>(latent, raw, rawhl, nrm, tsa);
    finalize_kernel<<<1, 256, 0, stream>>>(tsa, part, (float*)d_out);
}